// Round 3
// baseline (280.342 us; speedup 1.0000x reference)
//
#include <hip/hip_runtime.h>
#include <cstddef>

#define BATCH  8192
#define NFEAT  4096
#define NGRP   256
#define NSPLIT 253
#define NH1    512
#define NH2    256
#define EPSV   1e-5f

typedef __bf16 bf16_8 __attribute__((ext_vector_type(8)));
typedef float  f32x4  __attribute__((ext_vector_type(4)));

__constant__ int c_prefix[8] = {0,3,8,16,28,44,65,92};
__constant__ int c_gsize[8]  = {3,5,8,12,16,21,27,36};

// ---------------------------------------------------------------------------
// Kernel 1 (fused aux): blocks < 8192 compute one gene row; blocks
// [8192, 8576) do the three weight transposes (bf16, zero-padded K); the last
// block zeroes the stats buffer (replaces hipMemsetAsync).
// ---------------------------------------------------------------------------
__global__ __launch_bounds__(256) void gene_aux_kernel(
        const float* __restrict__ x, const float* __restrict__ wg,
        const float* __restrict__ bg, __bf16* __restrict__ geneb,
        const float* __restrict__ W1g1, const float* __restrict__ W2g1,
        const float* __restrict__ W2g2,
        __bf16* __restrict__ w1t, __bf16* __restrict__ w2at, __bf16* __restrict__ w2bt,
        float* __restrict__ st)
{
    __shared__ __align__(16) char smem[(NFEAT + 32 * 8) * 4 + NGRP * 4];
    int t = threadIdx.x;
    int bid = blockIdx.x;

    if (bid >= 8192) {
        int j = bid - 8192;
        if (j == 384) {           // stats zero: 4096 floats
            float4 z = {0.f, 0.f, 0.f, 0.f};
#pragma unroll
            for (int i = 0; i < 4; i++) *(float4*)&st[(t + 256 * i) * 4] = z;
            return;
        }
        // transpose job
        float (*tile)[33] = (float(*)[33])smem;
        int z = j >> 7, tid = j & 127;
        const float* src; __bf16* dst; int K, N, Kp;
        if (z == 0)      { src = W1g1; dst = w1t;  K = NSPLIT; N = NH1; Kp = 256; }
        else if (z == 1) { src = W2g1; dst = w2at; K = NH1;    N = NH2; Kp = NH1; }
        else             { src = W2g2; dst = w2bt; K = NH1;    N = NH2; Kp = NH1; }
        int ktiles = (K + 31) >> 5;
        if (tid >= ktiles * (N >> 5)) return;
        int kt = (tid % ktiles) * 32, nt = (tid / ktiles) * 32;
        int tx = t & 31, ty = t >> 5;
        for (int r = ty; r < 32; r += 8) {
            int k = kt + r, n = nt + tx;
            tile[r][tx] = (k < K && n < N) ? src[(size_t)k * N + n] : 0.f;
        }
        __syncthreads();
        for (int r = ty; r < 32; r += 8) {
            int n = nt + r, k = kt + tx;
            if (n < N && k < Kp) dst[(size_t)n * Kp + k] = (__bf16)tile[tx][r];
        }
        return;
    }

    // ---------------- gene row ----------------
    float* prod = (float*)smem;                    // NFEAT + 256 floats
    float* gout = prod + NFEAT + 32 * 8;           // NGRP floats
    size_t row = bid;
    const float4* xv = (const float4*)(x + row * NFEAT);
    const float4* wv = (const float4*)wg;
#pragma unroll
    for (int i = 0; i < 4; i++) {
        int idx = t + 256 * i;
        float4 a = xv[idx], w = wv[idx];
        float4 p; p.x = a.x*w.x; p.y = a.y*w.y; p.z = a.z*w.z; p.w = a.w*w.w;
        int f = idx * 4;
        *(float4*)&prod[f + ((f >> 7) << 3)] = p;
    }
    __syncthreads();
    int sub = t & 7, gidx = t >> 3;
    int gi  = gidx & 7, fbo = gidx >> 3;
    int pre = c_prefix[gi], len = c_gsize[gi];
#pragma unroll
    for (int s = 0; s < 8; s++) {
        int base = (4 * s + fbo) * 136 + pre;
        float v = 0.f;
        for (int j = sub; j < len; j += 8) v += prod[base + j];
        v += __shfl_down(v, 4, 8);
        v += __shfl_down(v, 2, 8);
        v += __shfl_down(v, 1, 8);
        if (sub == 0) gout[(s << 5) + gidx] = v;
    }
    __syncthreads();
    if (t < 32) {   // pack 8 bf16 per lane -> one uint4 store
        unsigned short up[8];
#pragma unroll
        for (int e = 0; e < 8; e++) {
            int g = t * 8 + e;
            __bf16 b = (__bf16)fmaxf(gout[g] + bg[g], 0.f);
            up[e] = *(unsigned short*)&b;
        }
        *(uint4*)((unsigned short*)geneb + row * NGRP + t * 8) = *(uint4*)up;
    }
}

// ---------------------------------------------------------------------------
// GEMM1 + fused b2l1: grid 1152 linear. XCD-swizzled: all 9 blocks of one
// m-panel land on the same XCD (L%8) so the geneb A-panel is fetched into
// one L2 instead of 8. x<8: 64x64 MFMA tile, B (w1t, 256KB L2-hot) read
// directly from global per fragment (no LDS staging). x==8: b2l1 K=3 branch.
// LDS 9.7KB.
// ---------------------------------------------------------------------------
__global__ __launch_bounds__(256) void gemm1_fused(
    const __bf16* __restrict__ geneb, const __bf16* __restrict__ w1t,
    const float* __restrict__ b1g1, __bf16* __restrict__ h1pre,
    float* __restrict__ s1a, float* __restrict__ q1a,
    const float* __restrict__ W1g2, const float* __restrict__ b1g2,
    __bf16* __restrict__ bufA, float* __restrict__ s2a, float* __restrict__ q2a)
{
    __shared__ __align__(16) char smem[9984];
    int t = threadIdx.x;

    // XCD swizzle: L -> (x, y) with all 9 x-blocks of a panel on one XCD.
    // L = (y%8) + 8*(9*(y/8) + x); inverse: g=L&7, c=L>>3, y=g+8*(c/9), x=c%9.
    int L = blockIdx.x;
    int g = L & 7, cc = L >> 3;
    int yq = cc / 9;
    int bx = cc - 9 * yq;
    int by = g + 8 * yq;

    if (bx == 8) {
        float* Ws  = (float*)smem;   // NOTE: needs 1536+512+192 floats = 8.96KB <= smem
        float* bsh = Ws + 1536;
        float* gv  = bsh + 512;
        for (int i = t; i < 1536; i += 256) Ws[i] = W1g2[i];
        for (int i = t; i < 512; i += 256) bsh[i] = b1g2[i];
        int row0 = by * 64;
        if (t < 192)
            gv[t] = (float)geneb[(size_t)(row0 + t / 3) * NGRP + NSPLIT + (t % 3)];
        __syncthreads();
        int c0 = t, c1 = t + 256;
        float s0 = 0, q0 = 0, s1 = 0, q1 = 0;
        for (int r = 0; r < 64; r++) {
            float a = gv[3 * r], b = gv[3 * r + 1], c = gv[3 * r + 2];
            float v0 = bsh[c0] + a * Ws[c0] + b * Ws[512 + c0] + c * Ws[1024 + c0];
            float v1 = bsh[c1] + a * Ws[c1] + b * Ws[512 + c1] + c * Ws[1024 + c1];
            size_t base = (size_t)(row0 + r) * NH1;
            bufA[base + c0] = (__bf16)v0; bufA[base + c1] = (__bf16)v1;
            s0 += v0; q0 += v0 * v0; s1 += v1; q1 += v1 * v1;
        }
        atomicAdd(&s2a[c0], s0); atomicAdd(&q2a[c0], q0);
        atomicAdd(&s2a[c1], s1); atomicAdd(&q2a[c1], q1);
        return;
    }

    const int K = 256;
    __bf16 (*As)[72] = (__bf16(*)[72])smem;          // 9216 B
    float* sred = (float*)(smem + 9216);             // 64
    float* qred = sred + 64;                         // 64  (9216+512 <= 9984)

    int n0 = bx * 64;
    int m0 = by * 64;
    if (t < 64) { sred[t] = 0.f; qred[t] = 0.f; }

    int lane = t & 63, w = t >> 6;
    int wm = (w & 1) * 32, wn = (w >> 1) * 32;
    int fm = lane & 15, quad = lane >> 4;

    f32x4 acc[2][2];
#pragma unroll
    for (int i = 0; i < 2; i++)
#pragma unroll
        for (int j = 0; j < 2; j++) acc[i][j] = (f32x4){0.f, 0.f, 0.f, 0.f};

    int r0 = t >> 3;
    int kc = (t & 7) * 8;
    const __bf16* Brow0 = w1t + (size_t)(n0 + wn + fm) * K;
    const __bf16* Brow1 = w1t + (size_t)(n0 + wn + 16 + fm) * K;

    for (int kt = 0; kt < (K >> 6); kt++) {
        int kk = kt << 6;
        __syncthreads();
#pragma unroll
        for (int h = 0; h < 2; h++) {
            int row = r0 + h * 32;
            *(uint4*)&As[row][kc] = *(const uint4*)(geneb + (size_t)(m0 + row) * NGRP + kk + kc);
        }
        __syncthreads();
#pragma unroll
        for (int kc2 = 0; kc2 < 64; kc2 += 32) {
            bf16_8 a0 = *(const bf16_8*)&As[wm + fm][kc2 + quad * 8];
            bf16_8 a1 = *(const bf16_8*)&As[wm + 16 + fm][kc2 + quad * 8];
            bf16_8 b0 = *(const bf16_8*)&Brow0[kk + kc2 + quad * 8];
            bf16_8 b1 = *(const bf16_8*)&Brow1[kk + kc2 + quad * 8];
            acc[0][0] = __builtin_amdgcn_mfma_f32_16x16x32_bf16(a0, b0, acc[0][0], 0, 0, 0);
            acc[0][1] = __builtin_amdgcn_mfma_f32_16x16x32_bf16(a0, b1, acc[0][1], 0, 0, 0);
            acc[1][0] = __builtin_amdgcn_mfma_f32_16x16x32_bf16(a1, b0, acc[1][0], 0, 0, 0);
            acc[1][1] = __builtin_amdgcn_mfma_f32_16x16x32_bf16(a1, b1, acc[1][1], 0, 0, 0);
        }
    }

    float myS[2] = {0.f, 0.f}, myQ[2] = {0.f, 0.f};
#pragma unroll
    for (int j = 0; j < 2; j++) {
        int col = n0 + wn + j * 16 + fm;
        float bv = b1g1[col];
#pragma unroll
        for (int i = 0; i < 2; i++)
#pragma unroll
            for (int r = 0; r < 4; r++) {
                float v = acc[i][j][r] + bv;
                int row = m0 + wm + i * 16 + quad * 4 + r;
                h1pre[(size_t)row * NH1 + col] = (__bf16)v;
                myS[j] += v; myQ[j] += v * v;
            }
    }
#pragma unroll
    for (int j = 0; j < 2; j++) {
        atomicAdd(&sred[wn + j * 16 + fm], myS[j]);
        atomicAdd(&qred[wn + j * 16 + fm], myQ[j]);
    }
    __syncthreads();
    if (t < 64) {
        atomicAdd(&s1a[n0 + t], sred[t]);
        atomicAdd(&q1a[n0 + t], qred[t]);
    }
}

// ---------------------------------------------------------------------------
// GEMM2 dual: grid (512, 1, 2) linear-x. XCD-swizzled so the 4 n-blocks of
// one m-panel share an XCD (A-panel fetched once per L2). B (w2at/w2bt,
// 256KB L2-hot) read directly from global per fragment. BN+ReLU fused on
// A-load. LDS 13.9KB.
// ---------------------------------------------------------------------------
__global__ __launch_bounds__(256) void gemm2_dual(
    const __bf16* A0, const __bf16* A1,
    const __bf16* WT0, const __bf16* WT1,
    const float* bias0, const float* bias1,
    __bf16* C0, __bf16* C1,
    float* csum0, float* csq0, float* csum1, float* csq1,
    const float* as0, const float* aq0, const float* ag0, const float* ab0,
    const float* as1, const float* aq1, const float* ag1, const float* ab1)
{
    const int K = NH1, n_total = NH2;
    __shared__ __align__(16) __bf16 As[64][72];
    __shared__ float bnsc[NH1];
    __shared__ float bnsh[NH1];
    __shared__ float sred[64];
    __shared__ float qred[64];

    int z = blockIdx.z;
    const __bf16* A    = z ? A1 : A0;
    const __bf16* WT   = z ? WT1 : WT0;
    const float*  bias = z ? bias1 : bias0;
    __bf16*       C    = z ? C1 : C0;
    float* csum = z ? csum1 : csum0;
    float* csq  = z ? csq1  : csq0;
    const float* a_sum = z ? as1 : as0;
    const float* a_sq  = z ? aq1 : aq0;
    const float* a_g   = z ? ag1 : ag0;
    const float* a_b   = z ? ab1 : ab0;

    // XCD swizzle: L = (y%8) + 8*(4*(y/8) + x); g=L&7, c=L>>3,
    // y = g + 8*(c/4), x = c%4.
    int L = blockIdx.x;
    int g = L & 7, cc = L >> 3;
    int yq = cc >> 2;
    int bx = cc & 3;
    int by = g + 8 * yq;

    int t = threadIdx.x;
    int n0 = bx * 64;
    int m0 = by * 64;
    {
        const float invB = 1.f / (float)BATCH;
        for (int k = t; k < K; k += 256) {
            float mu  = a_sum[k] * invB;
            float var = a_sq[k] * invB - mu * mu;
            float sc  = a_g[k] * rsqrtf(var + EPSV);
            bnsc[k] = sc;
            bnsh[k] = a_b[k] - mu * sc;
        }
    }
    if (t < 64) { sred[t] = 0.f; qred[t] = 0.f; }

    int lane = t & 63, w = t >> 6;
    int wm = (w & 1) * 32, wn = (w >> 1) * 32;
    int fm = lane & 15, quad = lane >> 4;

    f32x4 acc[2][2];
#pragma unroll
    for (int i = 0; i < 2; i++)
#pragma unroll
        for (int j = 0; j < 2; j++) acc[i][j] = (f32x4){0.f, 0.f, 0.f, 0.f};

    int r0 = t >> 3;
    int kc = (t & 7) * 8;
    const __bf16* Brow0 = WT + (size_t)(n0 + wn + fm) * K;
    const __bf16* Brow1 = WT + (size_t)(n0 + wn + 16 + fm) * K;

    for (int kt = 0; kt < (K >> 6); kt++) {
        int kk = kt << 6;
        __syncthreads();
#pragma unroll
        for (int h = 0; h < 2; h++) {
            int row = r0 + h * 32;
            uint4 raw = *(const uint4*)(A + (size_t)(m0 + row) * K + kk + kc);
            __bf16 vals[8];
#pragma unroll
            for (int c = 0; c < 4; c++) {
                unsigned uu = (&raw.x)[c];
                int kg = kk + kc + 2 * c;
                float flo = __uint_as_float(uu << 16);
                float fhi = __uint_as_float(uu & 0xffff0000u);
                flo = fmaxf(fmaf(flo, bnsc[kg],     bnsh[kg]),     0.f);
                fhi = fmaxf(fmaf(fhi, bnsc[kg + 1], bnsh[kg + 1]), 0.f);
                vals[2 * c]     = (__bf16)flo;
                vals[2 * c + 1] = (__bf16)fhi;
            }
            *(bf16_8*)&As[row][kc] = *(bf16_8*)vals;
        }
        __syncthreads();
#pragma unroll
        for (int kc2 = 0; kc2 < 64; kc2 += 32) {
            bf16_8 a0 = *(const bf16_8*)&As[wm + fm][kc2 + quad * 8];
            bf16_8 a1 = *(const bf16_8*)&As[wm + 16 + fm][kc2 + quad * 8];
            bf16_8 b0 = *(const bf16_8*)&Brow0[kk + kc2 + quad * 8];
            bf16_8 b1 = *(const bf16_8*)&Brow1[kk + kc2 + quad * 8];
            acc[0][0] = __builtin_amdgcn_mfma_f32_16x16x32_bf16(a0, b0, acc[0][0], 0, 0, 0);
            acc[0][1] = __builtin_amdgcn_mfma_f32_16x16x32_bf16(a0, b1, acc[0][1], 0, 0, 0);
            acc[1][0] = __builtin_amdgcn_mfma_f32_16x16x32_bf16(a1, b0, acc[1][0], 0, 0, 0);
            acc[1][1] = __builtin_amdgcn_mfma_f32_16x16x32_bf16(a1, b1, acc[1][1], 0, 0, 0);
        }
    }

    float myS[2] = {0.f, 0.f}, myQ[2] = {0.f, 0.f};
#pragma unroll
    for (int j = 0; j < 2; j++) {
        int col = n0 + wn + j * 16 + fm;
        float bv = bias[col];
#pragma unroll
        for (int i = 0; i < 2; i++)
#pragma unroll
            for (int r = 0; r < 4; r++) {
                float v = acc[i][j][r] + bv;
                int row = m0 + wm + i * 16 + quad * 4 + r;
                C[(size_t)row * n_total + col] = (__bf16)v;
                myS[j] += v; myQ[j] += v * v;
            }
    }
#pragma unroll
    for (int j = 0; j < 2; j++) {
        atomicAdd(&sred[wn + j * 16 + fm], myS[j]);
        atomicAdd(&qred[wn + j * 16 + fm], myQ[j]);
    }
    __syncthreads();
    if (t < 64) {
        atomicAdd(&csum[n0 + t], sred[t]);
        atomicAdd(&csq[n0 + t], qred[t]);
    }
}

// ---------------------------------------------------------------------------
// Final: out[b] = bnrelu(h1b)@Wout[0:256] + bnrelu(h2b)@Wout[256:512]
//               + geneb[b,:]@Wres + b_out + b_res.
// One wave per 4 rows (params loaded once, reused), 4 cols/lane.
// ---------------------------------------------------------------------------
__global__ __launch_bounds__(256) void final_kernel(
    const __bf16* __restrict__ h1, const __bf16* __restrict__ h2,
    const __bf16* __restrict__ geneb,
    const float* __restrict__ s1, const float* __restrict__ q1,
    const float* __restrict__ gm1, const float* __restrict__ bt1,
    const float* __restrict__ s2, const float* __restrict__ q2,
    const float* __restrict__ gm2, const float* __restrict__ bt2,
    const float* __restrict__ Wout, const float* __restrict__ bo,
    const float* __restrict__ Wres, const float* __restrict__ br,
    float* __restrict__ outp)
{
    int t = threadIdx.x, lane = t & 63, wv = t >> 6;
    int row0 = blockIdx.x * 16 + wv * 4;
    int c = lane * 4;
    const float invB = 1.f / (float)BATCH;
    float4 vs1 = *(const float4*)&s1[c],  vq1 = *(const float4*)&q1[c];
    float4 vg1 = *(const float4*)&gm1[c], vb1 = *(const float4*)&bt1[c];
    float4 vs2 = *(const float4*)&s2[c],  vq2 = *(const float4*)&q2[c];
    float4 vg2 = *(const float4*)&gm2[c], vb2 = *(const float4*)&bt2[c];
    float4 wo1 = *(const float4*)&Wout[c];
    float4 wo2 = *(const float4*)&Wout[NH2 + c];
    float4 wr  = *(const float4*)&Wres[c];
    // precompute BN affine per column: v = h*sc + sh
    float4 sc1, sh1, sc2, sh2;
#pragma unroll
    for (int e = 0; e < 4; e++) {
        float mu  = (&vs1.x)[e] * invB;
        float var = (&vq1.x)[e] * invB - mu * mu;
        float sc  = (&vg1.x)[e] * rsqrtf(var + EPSV);
        (&sc1.x)[e] = sc; (&sh1.x)[e] = (&vb1.x)[e] - mu * sc;
        mu  = (&vs2.x)[e] * invB;
        var = (&vq2.x)[e] * invB - mu * mu;
        sc  = (&vg2.x)[e] * rsqrtf(var + EPSV);
        (&sc2.x)[e] = sc; (&sh2.x)[e] = (&vb2.x)[e] - mu * sc;
    }
#pragma unroll
    for (int rr = 0; rr < 4; rr++) {
        int row = row0 + rr;
        ushort4 u1 = *(const ushort4*)((const unsigned short*)h1 + (size_t)row * NH2 + c);
        ushort4 u2 = *(const ushort4*)((const unsigned short*)h2 + (size_t)row * NH2 + c);
        ushort4 ug = *(const ushort4*)((const unsigned short*)geneb + (size_t)row * NGRP + c);
        float acc = 0.f;
#pragma unroll
        for (int e = 0; e < 4; e++) {
            float h1f = __uint_as_float((unsigned)(&u1.x)[e] << 16);
            float h2f = __uint_as_float((unsigned)(&u2.x)[e] << 16);
            float gvf = __uint_as_float((unsigned)(&ug.x)[e] << 16);
            acc += fmaxf(fmaf(h1f, (&sc1.x)[e], (&sh1.x)[e]), 0.f) * (&wo1.x)[e];
            acc += fmaxf(fmaf(h2f, (&sc2.x)[e], (&sh2.x)[e]), 0.f) * (&wo2.x)[e];
            acc += gvf * (&wr.x)[e];
        }
#pragma unroll
        for (int off = 32; off > 0; off >>= 1) acc += __shfl_down(acc, off, 64);
        if (lane == 0) outp[row] = acc + bo[0] + br[0];
    }
}

extern "C" void kernel_launch(void* const* d_in, const int* in_sizes, int n_in,
                              void* d_out, int out_size, void* d_ws, size_t ws_size,
                              hipStream_t stream)
{
    (void)in_sizes; (void)n_in; (void)out_size; (void)ws_size;
    const float* x        = (const float*)d_in[0];
    const float* wgene    = (const float*)d_in[2];
    const float* bgene    = (const float*)d_in[3];
    const float* W1g1     = (const float*)d_in[4];
    const float* b1g1     = (const float*)d_in[5];
    const float* W2g1     = (const float*)d_in[6];
    const float* b2g1     = (const float*)d_in[7];
    const float* W1g2     = (const float*)d_in[8];
    const float* b1g2     = (const float*)d_in[9];
    const float* W2g2     = (const float*)d_in[10];
    const float* b2g2     = (const float*)d_in[11];
    const float* gamma1g1 = (const float*)d_in[12];
    const float* beta1g1  = (const float*)d_in[13];
    const float* gamma2g1 = (const float*)d_in[14];
    const float* beta2g1  = (const float*)d_in[15];
    const float* gamma1g2 = (const float*)d_in[16];
    const float* beta1g2  = (const float*)d_in[17];
    const float* gamma2g2 = (const float*)d_in[18];
    const float* beta2g2  = (const float*)d_in[19];
    const float* Wout     = (const float*)d_in[20];
    const float* bout     = (const float*)d_in[21];
    const float* Wres     = (const float*)d_in[22];
    const float* bres     = (const float*)d_in[23];
    float* outp = (float*)d_out;

    char* p = (char*)d_ws;
    __bf16* geneb = (__bf16*)p;           p += (size_t)BATCH * NGRP * 2;
    __bf16* h1pre = (__bf16*)p;           p += (size_t)BATCH * NH1 * 2;
    __bf16* bufA  = (__bf16*)p;           p += (size_t)BATCH * NH1 * 2;
    __bf16* h1b   = (__bf16*)p;           p += (size_t)BATCH * NH2 * 2;
    __bf16* h2b   = (__bf16*)p;           p += (size_t)BATCH * NH2 * 2;
    __bf16* w1t   = (__bf16*)p;           p += (size_t)NH1 * 256 * 2;
    __bf16* w2at  = (__bf16*)p;           p += (size_t)NH2 * NH1 * 2;
    __bf16* w2bt  = (__bf16*)p;           p += (size_t)NH2 * NH1 * 2;
    float*  st    = (float*)p;
    float* s1a = st;          float* q1a = st + 512;
    float* s1b = st + 1024;   float* q1b = st + 1536;
    float* s2a = st + 2048;   float* q2a = st + 2560;
    float* s2b = st + 3072;   float* q2b = st + 3584;

    // gene rows + weight transposes + stat zeroing, one launch
    gene_aux_kernel<<<8192 + 384 + 1, 256, 0, stream>>>(
        x, wgene, bgene, geneb, W1g1, W2g1, W2g2, w1t, w2at, w2bt, st);

    // layer1: branch1 MFMA GEMM + branch2 K=3, XCD-swizzled linear grid
    gemm1_fused<<<9 * (BATCH / 64), 256, 0, stream>>>(
        geneb, w1t, b1g1, h1pre, s1a, q1a,
        W1g2, b1g2, bufA, s2a, q2a);

    // layer2 both branches, XCD-swizzled linear grid per z
    gemm2_dual<<<dim3((NH2 / 64) * (BATCH / 64), 1, 2), 256, 0, stream>>>(
        h1pre, bufA, w2at, w2bt, b2g1, b2g2, h1b, h2b,
        s1b, q1b, s2b, q2b,
        s1a, q1a, gamma1g1, beta1g1,
        s2a, q2a, gamma1g2, beta1g2);

    final_kernel<<<BATCH / 16, 256, 0, stream>>>(
        h1b, h2b, geneb,
        s1b, q1b, gamma2g1, beta2g1,
        s2b, q2b, gamma2g2, beta2g2,
        Wout, bout, Wres, bres, outp);
}

// Round 4
// 274.347 us; speedup vs baseline: 1.0219x; 1.0219x over previous
//
#include <hip/hip_runtime.h>
#include <cstddef>

#define BATCH  8192
#define NFEAT  4096
#define NGRP   256
#define NSPLIT 253
#define NH1    512
#define NH2    256
#define EPSV   1e-5f

typedef __bf16 bf16_8 __attribute__((ext_vector_type(8)));
typedef float  f32x4  __attribute__((ext_vector_type(4)));

// Per 16-feature segment s (within a 128-feature pattern period):
// packed b0 | b1<<8 | gfirst<<16. Segment covers groups gfirst..gfirst+2 with
// element ranges [0,b0), [b0,b1), [b1,16). Unused ranges contribute exact 0.0f
// into the (padded) next slots.
__constant__ unsigned c_segtab[8] = {
    0x00000803u,  // s0: g0[0,3) g1[3,8) g2[8,16)
    0x0003100Cu,  // s1: g3[0,12) g4[12,16)
    0x0004100Cu,  // s2: g4[0,12) g5[12,16)
    0x00051010u,  // s3: g5[0,16)
    0x00051001u,  // s4: g5[0,1) g6[1,16)
    0x0006100Cu,  // s5: g6[0,12) g7[12,16)
    0x00071010u,  // s6: g7[0,16)
    0x00071010u   // s7: g7[0,16)
};

// ---------------------------------------------------------------------------
// Kernel 1 (fused aux): blocks < 8192 compute one gene row; blocks
// [8192, 8576) do the three weight transposes (bf16, zero-padded K); the last
// block zeroes the stats buffer (replaces hipMemsetAsync).
// gene row: thread t owns 16 consecutive features; PATTERN period = 128
// features/8 groups, so each 16-seg hits <=3 statically-known groups.
// Branchless 3-way split + 3 LDS atomicAdds; no 4096-float LDS roundtrip.
// LDS 4.4KB (was 17.4KB).
// ---------------------------------------------------------------------------
__global__ __launch_bounds__(256) void gene_aux_kernel(
        const float* __restrict__ x, const float* __restrict__ wg,
        const float* __restrict__ bg, __bf16* __restrict__ geneb,
        const float* __restrict__ W1g1, const float* __restrict__ W2g1,
        const float* __restrict__ W2g2,
        __bf16* __restrict__ w1t, __bf16* __restrict__ w2at, __bf16* __restrict__ w2bt,
        float* __restrict__ st)
{
    __shared__ __align__(16) char smem[4352];
    int t = threadIdx.x;
    int bid = blockIdx.x;

    if (bid >= 8192) {
        int j = bid - 8192;
        if (j == 384) {           // stats zero: 4096 floats
            float4 z = {0.f, 0.f, 0.f, 0.f};
#pragma unroll
            for (int i = 0; i < 4; i++) *(float4*)&st[(t + 256 * i) * 4] = z;
            return;
        }
        // transpose job
        float (*tile)[33] = (float(*)[33])smem;
        int z = j >> 7, tid = j & 127;
        const float* src; __bf16* dst; int K, N, Kp;
        if (z == 0)      { src = W1g1; dst = w1t;  K = NSPLIT; N = NH1; Kp = 256; }
        else if (z == 1) { src = W2g1; dst = w2at; K = NH1;    N = NH2; Kp = NH1; }
        else             { src = W2g2; dst = w2bt; K = NH1;    N = NH2; Kp = NH1; }
        int ktiles = (K + 31) >> 5;
        if (tid >= ktiles * (N >> 5)) return;
        int kt = (tid % ktiles) * 32, nt = (tid / ktiles) * 32;
        int tx = t & 31, ty = t >> 5;
        for (int r = ty; r < 32; r += 8) {
            int k = kt + r, n = nt + tx;
            tile[r][tx] = (k < K && n < N) ? src[(size_t)k * N + n] : 0.f;
        }
        __syncthreads();
        for (int r = ty; r < 32; r += 8) {
            int n = nt + r, k = kt + tx;
            if (n < N && k < Kp) dst[(size_t)n * Kp + k] = (__bf16)tile[tx][r];
        }
        return;
    }

    // ---------------- gene row (register path) ----------------
    float* gacc = (float*)smem;              // 272 floats (256 + 16 pad)
    size_t row = bid;

    gacc[t] = 0.f;
    if (t < 16) gacc[256 + t] = 0.f;

    const float4* xv = (const float4*)(x + row * NFEAT + (size_t)t * 16);
    const float4* wv = (const float4*)(wg + (size_t)t * 16);
    float p[16];
#pragma unroll
    for (int i = 0; i < 4; i++) {
        float4 a = xv[i], w = wv[i];
        p[4*i+0] = a.x*w.x; p[4*i+1] = a.y*w.y;
        p[4*i+2] = a.z*w.z; p[4*i+3] = a.w*w.w;
    }

    unsigned tab = c_segtab[t & 7];
    int b0 = tab & 0xff, b1 = (tab >> 8) & 0xff, gf = tab >> 16;
    float a0 = 0.f, a1 = 0.f, a2 = 0.f;
#pragma unroll
    for (int e = 0; e < 16; e++) {
        float v = p[e];
        a0 += (e <  b0)            ? v : 0.f;
        a1 += (e >= b0 && e < b1)  ? v : 0.f;
        a2 += (e >= b1)            ? v : 0.f;
    }
    __syncthreads();   // gacc zeroed before atomics
    int gb = (t >> 3) * 8 + gf;
    atomicAdd(&gacc[gb],     a0);
    atomicAdd(&gacc[gb + 1], a1);
    atomicAdd(&gacc[gb + 2], a2);
    __syncthreads();

    if (t < 32) {   // pack 8 bf16 per lane -> one uint4 store
        unsigned short up[8];
#pragma unroll
        for (int e = 0; e < 8; e++) {
            int g = t * 8 + e;
            __bf16 b = (__bf16)fmaxf(gacc[g] + bg[g], 0.f);
            up[e] = *(unsigned short*)&b;
        }
        *(uint4*)((unsigned short*)geneb + row * NGRP + t * 8) = *(uint4*)up;
    }
}

// ---------------------------------------------------------------------------
// GEMM1 + fused b2l1: grid (9, 128). x<8: 64x64 MFMA tile of
// h1pre = geneb @ w1t^T + b1g1 (stats s1a/q1a). x==8: b2l1 for 64 rows:
// bufA = geneb[:,253:256] @ W1g2 + b1g2 (stats s2a/q2a).
// LDS 19.4 KB -> 8 blocks/CU residency cap (grid is 4.5/CU).
// [R0/R2-verified structure: LDS B staging, no swizzle]
// ---------------------------------------------------------------------------
__global__ __launch_bounds__(256) void gemm1_fused(
    const __bf16* __restrict__ geneb, const __bf16* __restrict__ w1t,
    const float* __restrict__ b1g1, __bf16* __restrict__ h1pre,
    float* __restrict__ s1a, float* __restrict__ q1a,
    const float* __restrict__ W1g2, const float* __restrict__ b1g2,
    __bf16* __restrict__ bufA, float* __restrict__ s2a, float* __restrict__ q2a)
{
    __shared__ __align__(16) char smem[19456];
    int t = threadIdx.x;

    if (blockIdx.x == 8) {
        float* Ws  = (float*)smem;
        float* bsh = Ws + 1536;
        float* gv  = bsh + 512;
        for (int i = t; i < 1536; i += 256) Ws[i] = W1g2[i];
        for (int i = t; i < 512; i += 256) bsh[i] = b1g2[i];
        int row0 = blockIdx.y * 64;
        if (t < 192)
            gv[t] = (float)geneb[(size_t)(row0 + t / 3) * NGRP + NSPLIT + (t % 3)];
        __syncthreads();
        int c0 = t, c1 = t + 256;
        float s0 = 0, q0 = 0, s1 = 0, q1 = 0;
        for (int r = 0; r < 64; r++) {
            float a = gv[3 * r], b = gv[3 * r + 1], c = gv[3 * r + 2];
            float v0 = bsh[c0] + a * Ws[c0] + b * Ws[512 + c0] + c * Ws[1024 + c0];
            float v1 = bsh[c1] + a * Ws[c1] + b * Ws[512 + c1] + c * Ws[1024 + c1];
            size_t base = (size_t)(row0 + r) * NH1;
            bufA[base + c0] = (__bf16)v0; bufA[base + c1] = (__bf16)v1;
            s0 += v0; q0 += v0 * v0; s1 += v1; q1 += v1 * v1;
        }
        atomicAdd(&s2a[c0], s0); atomicAdd(&q2a[c0], q0);
        atomicAdd(&s2a[c1], s1); atomicAdd(&q2a[c1], q1);
        return;
    }

    const int K = 256;
    __bf16 (*As)[72] = (__bf16(*)[72])smem;
    __bf16 (*Bs)[72] = (__bf16(*)[72])(smem + 9216);
    float* sred = (float*)(smem + 18432);
    float* qred = sred + 64;

    int n0 = blockIdx.x * 64;
    int m0 = blockIdx.y * 64;
    if (t < 64) { sred[t] = 0.f; qred[t] = 0.f; }

    int lane = t & 63, w = t >> 6;
    int wm = (w & 1) * 32, wn = (w >> 1) * 32;
    int fm = lane & 15, quad = lane >> 4;

    f32x4 acc[2][2];
#pragma unroll
    for (int i = 0; i < 2; i++)
#pragma unroll
        for (int j = 0; j < 2; j++) acc[i][j] = (f32x4){0.f, 0.f, 0.f, 0.f};

    int r0 = t >> 3;
    int kc = (t & 7) * 8;

    for (int kt = 0; kt < (K >> 6); kt++) {
        int kk = kt << 6;
        __syncthreads();
#pragma unroll
        for (int h = 0; h < 2; h++) {
            int row = r0 + h * 32;
            *(uint4*)&As[row][kc] = *(const uint4*)(geneb + (size_t)(m0 + row) * NGRP + kk + kc);
            *(uint4*)&Bs[row][kc] = *(const uint4*)(w1t + (size_t)(n0 + row) * K + kk + kc);
        }
        __syncthreads();
#pragma unroll
        for (int kc2 = 0; kc2 < 64; kc2 += 32) {
            bf16_8 a0 = *(const bf16_8*)&As[wm + fm][kc2 + quad * 8];
            bf16_8 a1 = *(const bf16_8*)&As[wm + 16 + fm][kc2 + quad * 8];
            bf16_8 b0 = *(const bf16_8*)&Bs[wn + fm][kc2 + quad * 8];
            bf16_8 b1 = *(const bf16_8*)&Bs[wn + 16 + fm][kc2 + quad * 8];
            acc[0][0] = __builtin_amdgcn_mfma_f32_16x16x32_bf16(a0, b0, acc[0][0], 0, 0, 0);
            acc[0][1] = __builtin_amdgcn_mfma_f32_16x16x32_bf16(a0, b1, acc[0][1], 0, 0, 0);
            acc[1][0] = __builtin_amdgcn_mfma_f32_16x16x32_bf16(a1, b0, acc[1][0], 0, 0, 0);
            acc[1][1] = __builtin_amdgcn_mfma_f32_16x16x32_bf16(a1, b1, acc[1][1], 0, 0, 0);
        }
    }

    float myS[2] = {0.f, 0.f}, myQ[2] = {0.f, 0.f};
#pragma unroll
    for (int j = 0; j < 2; j++) {
        int col = n0 + wn + j * 16 + fm;
        float bv = b1g1[col];
#pragma unroll
        for (int i = 0; i < 2; i++)
#pragma unroll
            for (int r = 0; r < 4; r++) {
                float v = acc[i][j][r] + bv;
                int row = m0 + wm + i * 16 + quad * 4 + r;
                h1pre[(size_t)row * NH1 + col] = (__bf16)v;
                myS[j] += v; myQ[j] += v * v;
            }
    }
#pragma unroll
    for (int j = 0; j < 2; j++) {
        atomicAdd(&sred[wn + j * 16 + fm], myS[j]);
        atomicAdd(&qred[wn + j * 16 + fm], myQ[j]);
    }
    __syncthreads();
    if (t < 64) {
        atomicAdd(&s1a[n0 + t], sred[t]);
        atomicAdd(&q1a[n0 + t], qred[t]);
    }
}

// ---------------------------------------------------------------------------
// GEMM2 dual (both branches, blockIdx.z selects): K=512, N=256, BN+ReLU fused
// on A-load from batch stats. 64x64 tiles (verified round-0 config).
// ---------------------------------------------------------------------------
__global__ __launch_bounds__(256) void gemm2_dual(
    const __bf16* A0, const __bf16* A1,
    const __bf16* WT0, const __bf16* WT1,
    const float* bias0, const float* bias1,
    __bf16* C0, __bf16* C1,
    float* csum0, float* csq0, float* csum1, float* csq1,
    const float* as0, const float* aq0, const float* ag0, const float* ab0,
    const float* as1, const float* aq1, const float* ag1, const float* ab1)
{
    const int K = NH1, n_total = NH2;
    __shared__ __align__(16) __bf16 As[64][72];
    __shared__ __align__(16) __bf16 Bs[64][72];
    __shared__ float bnsc[NH1];
    __shared__ float bnsh[NH1];
    __shared__ float sred[64];
    __shared__ float qred[64];

    int z = blockIdx.z;
    const __bf16* A    = z ? A1 : A0;
    const __bf16* WT   = z ? WT1 : WT0;
    const float*  bias = z ? bias1 : bias0;
    __bf16*       C    = z ? C1 : C0;
    float* csum = z ? csum1 : csum0;
    float* csq  = z ? csq1  : csq0;
    const float* a_sum = z ? as1 : as0;
    const float* a_sq  = z ? aq1 : aq0;
    const float* a_g   = z ? ag1 : ag0;
    const float* a_b   = z ? ab1 : ab0;

    int t = threadIdx.x;
    int n0 = blockIdx.x * 64;
    int m0 = blockIdx.y * 64;
    {
        const float invB = 1.f / (float)BATCH;
        for (int k = t; k < K; k += 256) {
            float mu  = a_sum[k] * invB;
            float var = a_sq[k] * invB - mu * mu;
            float sc  = a_g[k] * rsqrtf(var + EPSV);
            bnsc[k] = sc;
            bnsh[k] = a_b[k] - mu * sc;
        }
    }
    if (t < 64) { sred[t] = 0.f; qred[t] = 0.f; }

    int lane = t & 63, w = t >> 6;
    int wm = (w & 1) * 32, wn = (w >> 1) * 32;
    int fm = lane & 15, quad = lane >> 4;

    f32x4 acc[2][2];
#pragma unroll
    for (int i = 0; i < 2; i++)
#pragma unroll
        for (int j = 0; j < 2; j++) acc[i][j] = (f32x4){0.f, 0.f, 0.f, 0.f};

    int r0 = t >> 3;
    int kc = (t & 7) * 8;

    for (int kt = 0; kt < (K >> 6); kt++) {
        int kk = kt << 6;
        __syncthreads();
#pragma unroll
        for (int h = 0; h < 2; h++) {
            int row = r0 + h * 32;
            uint4 raw = *(const uint4*)(A + (size_t)(m0 + row) * K + kk + kc);
            __bf16 vals[8];
#pragma unroll
            for (int c = 0; c < 4; c++) {
                unsigned uu = (&raw.x)[c];
                int kg = kk + kc + 2 * c;
                float flo = __uint_as_float(uu << 16);
                float fhi = __uint_as_float(uu & 0xffff0000u);
                flo = fmaxf(fmaf(flo, bnsc[kg],     bnsh[kg]),     0.f);
                fhi = fmaxf(fmaf(fhi, bnsc[kg + 1], bnsh[kg + 1]), 0.f);
                vals[2 * c]     = (__bf16)flo;
                vals[2 * c + 1] = (__bf16)fhi;
            }
            *(bf16_8*)&As[row][kc] = *(bf16_8*)vals;
            *(uint4*)&Bs[row][kc] = *(const uint4*)(WT + (size_t)(n0 + row) * K + kk + kc);
        }
        __syncthreads();
#pragma unroll
        for (int kc2 = 0; kc2 < 64; kc2 += 32) {
            bf16_8 a0 = *(const bf16_8*)&As[wm + fm][kc2 + quad * 8];
            bf16_8 a1 = *(const bf16_8*)&As[wm + 16 + fm][kc2 + quad * 8];
            bf16_8 b0 = *(const bf16_8*)&Bs[wn + fm][kc2 + quad * 8];
            bf16_8 b1 = *(const bf16_8*)&Bs[wn + 16 + fm][kc2 + quad * 8];
            acc[0][0] = __builtin_amdgcn_mfma_f32_16x16x32_bf16(a0, b0, acc[0][0], 0, 0, 0);
            acc[0][1] = __builtin_amdgcn_mfma_f32_16x16x32_bf16(a0, b1, acc[0][1], 0, 0, 0);
            acc[1][0] = __builtin_amdgcn_mfma_f32_16x16x32_bf16(a1, b0, acc[1][0], 0, 0, 0);
            acc[1][1] = __builtin_amdgcn_mfma_f32_16x16x32_bf16(a1, b1, acc[1][1], 0, 0, 0);
        }
    }

    float myS[2] = {0.f, 0.f}, myQ[2] = {0.f, 0.f};
#pragma unroll
    for (int j = 0; j < 2; j++) {
        int col = n0 + wn + j * 16 + fm;
        float bv = bias[col];
#pragma unroll
        for (int i = 0; i < 2; i++)
#pragma unroll
            for (int r = 0; r < 4; r++) {
                float v = acc[i][j][r] + bv;
                int row = m0 + wm + i * 16 + quad * 4 + r;
                C[(size_t)row * n_total + col] = (__bf16)v;
                myS[j] += v; myQ[j] += v * v;
            }
    }
#pragma unroll
    for (int j = 0; j < 2; j++) {
        atomicAdd(&sred[wn + j * 16 + fm], myS[j]);
        atomicAdd(&qred[wn + j * 16 + fm], myQ[j]);
    }
    __syncthreads();
    if (t < 64) {
        atomicAdd(&csum[n0 + t], sred[t]);
        atomicAdd(&csq[n0 + t], qred[t]);
    }
}

// ---------------------------------------------------------------------------
// Final: out[b] = bnrelu(h1b)@Wout[0:256] + bnrelu(h2b)@Wout[256:512]
//               + geneb[b,:]@Wres + b_out + b_res.
// One wave per 4 rows (params loaded once, reused), 4 cols/lane.
// ---------------------------------------------------------------------------
__global__ __launch_bounds__(256) void final_kernel(
    const __bf16* __restrict__ h1, const __bf16* __restrict__ h2,
    const __bf16* __restrict__ geneb,
    const float* __restrict__ s1, const float* __restrict__ q1,
    const float* __restrict__ gm1, const float* __restrict__ bt1,
    const float* __restrict__ s2, const float* __restrict__ q2,
    const float* __restrict__ gm2, const float* __restrict__ bt2,
    const float* __restrict__ Wout, const float* __restrict__ bo,
    const float* __restrict__ Wres, const float* __restrict__ br,
    float* __restrict__ outp)
{
    int t = threadIdx.x, lane = t & 63, wv = t >> 6;
    int row0 = blockIdx.x * 16 + wv * 4;
    int c = lane * 4;
    const float invB = 1.f / (float)BATCH;
    float4 vs1 = *(const float4*)&s1[c],  vq1 = *(const float4*)&q1[c];
    float4 vg1 = *(const float4*)&gm1[c], vb1 = *(const float4*)&bt1[c];
    float4 vs2 = *(const float4*)&s2[c],  vq2 = *(const float4*)&q2[c];
    float4 vg2 = *(const float4*)&gm2[c], vb2 = *(const float4*)&bt2[c];
    float4 wo1 = *(const float4*)&Wout[c];
    float4 wo2 = *(const float4*)&Wout[NH2 + c];
    float4 wr  = *(const float4*)&Wres[c];
    // precompute BN affine per column: v = h*sc + sh
    float4 sc1, sh1, sc2, sh2;
#pragma unroll
    for (int e = 0; e < 4; e++) {
        float mu  = (&vs1.x)[e] * invB;
        float var = (&vq1.x)[e] * invB - mu * mu;
        float sc  = (&vg1.x)[e] * rsqrtf(var + EPSV);
        (&sc1.x)[e] = sc; (&sh1.x)[e] = (&vb1.x)[e] - mu * sc;
        mu  = (&vs2.x)[e] * invB;
        var = (&vq2.x)[e] * invB - mu * mu;
        sc  = (&vg2.x)[e] * rsqrtf(var + EPSV);
        (&sc2.x)[e] = sc; (&sh2.x)[e] = (&vb2.x)[e] - mu * sc;
    }
#pragma unroll
    for (int rr = 0; rr < 4; rr++) {
        int row = row0 + rr;
        ushort4 u1 = *(const ushort4*)((const unsigned short*)h1 + (size_t)row * NH2 + c);
        ushort4 u2 = *(const ushort4*)((const unsigned short*)h2 + (size_t)row * NH2 + c);
        ushort4 ug = *(const ushort4*)((const unsigned short*)geneb + (size_t)row * NGRP + c);
        float acc = 0.f;
#pragma unroll
        for (int e = 0; e < 4; e++) {
            float h1f = __uint_as_float((unsigned)(&u1.x)[e] << 16);
            float h2f = __uint_as_float((unsigned)(&u2.x)[e] << 16);
            float gvf = __uint_as_float((unsigned)(&ug.x)[e] << 16);
            acc += fmaxf(fmaf(h1f, (&sc1.x)[e], (&sh1.x)[e]), 0.f) * (&wo1.x)[e];
            acc += fmaxf(fmaf(h2f, (&sc2.x)[e], (&sh2.x)[e]), 0.f) * (&wo2.x)[e];
            acc += gvf * (&wr.x)[e];
        }
#pragma unroll
        for (int off = 32; off > 0; off >>= 1) acc += __shfl_down(acc, off, 64);
        if (lane == 0) outp[row] = acc + bo[0] + br[0];
    }
}

extern "C" void kernel_launch(void* const* d_in, const int* in_sizes, int n_in,
                              void* d_out, int out_size, void* d_ws, size_t ws_size,
                              hipStream_t stream)
{
    (void)in_sizes; (void)n_in; (void)out_size; (void)ws_size;
    const float* x        = (const float*)d_in[0];
    const float* wgene    = (const float*)d_in[2];
    const float* bgene    = (const float*)d_in[3];
    const float* W1g1     = (const float*)d_in[4];
    const float* b1g1     = (const float*)d_in[5];
    const float* W2g1     = (const float*)d_in[6];
    const float* b2g1     = (const float*)d_in[7];
    const float* W1g2     = (const float*)d_in[8];
    const float* b1g2     = (const float*)d_in[9];
    const float* W2g2     = (const float*)d_in[10];
    const float* b2g2     = (const float*)d_in[11];
    const float* gamma1g1 = (const float*)d_in[12];
    const float* beta1g1  = (const float*)d_in[13];
    const float* gamma2g1 = (const float*)d_in[14];
    const float* beta2g1  = (const float*)d_in[15];
    const float* gamma1g2 = (const float*)d_in[16];
    const float* beta1g2  = (const float*)d_in[17];
    const float* gamma2g2 = (const float*)d_in[18];
    const float* beta2g2  = (const float*)d_in[19];
    const float* Wout     = (const float*)d_in[20];
    const float* bout     = (const float*)d_in[21];
    const float* Wres     = (const float*)d_in[22];
    const float* bres     = (const float*)d_in[23];
    float* outp = (float*)d_out;

    char* p = (char*)d_ws;
    __bf16* geneb = (__bf16*)p;           p += (size_t)BATCH * NGRP * 2;
    __bf16* h1pre = (__bf16*)p;           p += (size_t)BATCH * NH1 * 2;
    __bf16* bufA  = (__bf16*)p;           p += (size_t)BATCH * NH1 * 2;
    __bf16* h1b   = (__bf16*)p;           p += (size_t)BATCH * NH2 * 2;
    __bf16* h2b   = (__bf16*)p;           p += (size_t)BATCH * NH2 * 2;
    __bf16* w1t   = (__bf16*)p;           p += (size_t)NH1 * 256 * 2;
    __bf16* w2at  = (__bf16*)p;           p += (size_t)NH2 * NH1 * 2;
    __bf16* w2bt  = (__bf16*)p;           p += (size_t)NH2 * NH1 * 2;
    float*  st    = (float*)p;
    float* s1a = st;          float* q1a = st + 512;
    float* s1b = st + 1024;   float* q1b = st + 1536;
    float* s2a = st + 2048;   float* q2a = st + 2560;
    float* s2b = st + 3072;   float* q2b = st + 3584;

    // gene rows + weight transposes + stat zeroing, one launch
    gene_aux_kernel<<<8192 + 384 + 1, 256, 0, stream>>>(
        x, wgene, bgene, geneb, W1g1, W2g1, W2g2, w1t, w2at, w2bt, st);

    // layer1: branch1 MFMA GEMM (x<8) + branch2 K=3 (x==8)
    gemm1_fused<<<dim3(9, BATCH / 64), 256, 0, stream>>>(
        geneb, w1t, b1g1, h1pre, s1a, q1a,
        W1g2, b1g2, bufA, s2a, q2a);

    // layer2 both branches: bnrelu(A) @ WT^T + bias -> h1b/h2b, stats
    gemm2_dual<<<dim3(NH2 / 64, BATCH / 64, 2), 256, 0, stream>>>(
        h1pre, bufA, w2at, w2bt, b2g1, b2g2, h1b, h2b,
        s1b, q1b, s2b, q2b,
        s1a, q1a, gamma1g1, beta1g1,
        s2a, q2a, gamma1g2, beta1g2);

    final_kernel<<<BATCH / 16, 256, 0, stream>>>(
        h1b, h2b, geneb,
        s1b, q1b, gamma2g1, beta2g1,
        s2b, q2b, gamma2g2, beta2g2,
        Wout, bout, Wres, bres, outp);
}